// Round 2
// baseline (504.509 us; speedup 1.0000x reference)
//
#include <hip/hip_runtime.h>

#define F      128
#define OUT_W  384
#define NBLK   64    // counting-sort blocks
#define HT     512   // threads per hist/scatter block

typedef __attribute__((ext_vector_type(4))) float f4;

// ---------------------------------------------------------------------------
// K1: per-block LDS-privatized histogram of destinations. No global atomics.
//     Also zeroes the segment cursor for K2.
// ---------------------------------------------------------------------------
__global__ __launch_bounds__(HT) void hist_kernel(const int* __restrict__ row,
                                                  int* __restrict__ hist,
                                                  int* __restrict__ cursor,
                                                  int E, int N, int chunk) {
    extern __shared__ int h[];
    const int t = threadIdx.x;
    if (blockIdx.x == 0 && t == 0) *cursor = 0;
    for (int i = t; i < N; i += HT) h[i] = 0;
    __syncthreads();
    const int lo = blockIdx.x * chunk;
    const int hi = min(lo + chunk, E);
    for (int i = lo + t; i < hi; i += HT) atomicAdd(&h[row[i]], 1);
    __syncthreads();
    int* dst = hist + (size_t)blockIdx.x * N;
    for (int i = t; i < N; i += HT) dst[i] = h[i];
}

// ---------------------------------------------------------------------------
// K2 (fused, replaces totals+scan+blockstart): per-node degree over the NBLK
// block-histograms, segment start via wave-aggregated global cursor (segment
// ORDER is arbitrary — only disjointness matters), then per-block running
// starts written back into hist. One kernel, no inter-block dependency.
// ---------------------------------------------------------------------------
__global__ void assign_kernel(int* __restrict__ hist, int* __restrict__ segstart,
                              int* __restrict__ deg, int* __restrict__ cursor, int N) {
    const int n = blockIdx.x * blockDim.x + threadIdx.x;
    const int lane = threadIdx.x & 63;
    int s = 0;
    if (n < N)
        for (int b = 0; b < NBLK; ++b) s += hist[(size_t)b * N + n];
    // wave-wide inclusive scan of s -> one atomic per wave
    int incl = s;
    for (int d = 1; d < 64; d <<= 1) {
        int v = __shfl_up(incl, d);
        if (lane >= d) incl += v;
    }
    int base = 0;
    if (lane == 63) base = atomicAdd(cursor, incl);
    base = __shfl(base, 63);
    const int start = base + incl - s;          // exclusive prefix within wave
    if (n >= N) return;
    segstart[n] = start;
    deg[n]      = s;
    int run = start;
    for (int b = 0; b < NBLK; ++b) {
        const size_t k = (size_t)b * N + n;
        const int v = hist[k];
        hist[k] = run;
        run += v;
    }
}

// ---------------------------------------------------------------------------
// K3: place edge ids AND pre-gathered source ids. LDS cursors only.
// ---------------------------------------------------------------------------
__global__ __launch_bounds__(HT) void scatter_kernel(const int* __restrict__ row,
                                                     const int* __restrict__ col,
                                                     const int* __restrict__ hist,
                                                     int* __restrict__ eid,
                                                     int* __restrict__ cid,
                                                     int E, int N, int chunk) {
    extern __shared__ int cur[];
    const int t = threadIdx.x;
    const int* src = hist + (size_t)blockIdx.x * N;
    for (int i = t; i < N; i += HT) cur[i] = src[i];
    __syncthreads();
    const int lo = blockIdx.x * chunk;
    const int hi = min(lo + chunk, E);
    for (int i = lo + t; i < hi; i += HT) {
        const int p = atomicAdd(&cur[row[i]], 1);
        eid[p] = i;          // for edge_attr half
        cid[p] = col[i];     // for x-gather half (kills dependent gather in K4)
    }
}

// ---------------------------------------------------------------------------
// K4: aggregation. 2 waves per node: half 0 sums x[cid[*]] (L2/L3-resident),
// half 1 streams edge_attr[eid[*]] nontemporally. 8-edge unrolled inner loop
// -> 4 independent 16 B loads in flight per lane. No barriers.
// ---------------------------------------------------------------------------
template <bool NT>
__device__ __forceinline__ f4 row_ld(const float* __restrict__ mat, int id, int sub) {
    const f4* p = (const f4*)(mat + (size_t)id * F + sub * 4);
    return NT ? __builtin_nontemporal_load(p) : *p;
}

template <bool NT>
__device__ __forceinline__ void accum_half(const float* __restrict__ mat,
                                           const int* __restrict__ ids,
                                           int start, int end, int lane, f4& acc) {
    const int which = lane >> 5;
    const int sub   = lane & 31;
    for (int base = start; base < end; base += 64) {
        const int m = min(64, end - base);
        int idx = base + lane;
        if (idx >= end) idx = end - 1;          // clamp; lanes >= m never selected
        const int myid = ids[idx];
        int i = 0;
        for (; i + 8 <= m; i += 8) {
            const int id0 = __shfl(myid, i + 0 + which);
            const int id1 = __shfl(myid, i + 2 + which);
            const int id2 = __shfl(myid, i + 4 + which);
            const int id3 = __shfl(myid, i + 6 + which);
            const f4 v0 = row_ld<NT>(mat, id0, sub);
            const f4 v1 = row_ld<NT>(mat, id1, sub);
            const f4 v2 = row_ld<NT>(mat, id2, sub);
            const f4 v3 = row_ld<NT>(mat, id3, sub);
            acc += v0; acc += v1; acc += v2; acc += v3;
        }
        const int full = m & ~1;
        for (; i < full; i += 2) {
            const int id = __shfl(myid, i + which);
            acc += row_ld<NT>(mat, id, sub);
        }
        if (m & 1) {
            const int id = __shfl(myid, full);
            if (which == 0) acc += row_ld<NT>(mat, id, sub);
        }
    }
}

__global__ __launch_bounds__(256) void aggregate_kernel(
    const float* __restrict__ x, const float* __restrict__ edge_attr,
    const int* __restrict__ segstart, const int* __restrict__ deg,
    const int* __restrict__ eid, const int* __restrict__ cid,
    float* __restrict__ out, int N) {

    const int wave = threadIdx.x >> 6;
    const int lane = threadIdx.x & 63;
    const int wid  = blockIdx.x * 4 + wave;
    const int node = wid >> 1;
    const int half = wid & 1;
    if (node >= N) return;

    const int start = segstart[node];
    const int d     = deg[node];
    const int end   = start + d;

    f4 acc = {0.f, 0.f, 0.f, 0.f};
    if (half == 0) accum_half<false>(x,         cid, start, end, lane, acc);
    else           accum_half<true >(edge_attr, eid, start, end, lane, acc);

    // fold odd-edge lanes (32..63) into even-edge lanes (0..31)
    acc.x += __shfl_xor(acc.x, 32);
    acc.y += __shfl_xor(acc.y, 32);
    acc.z += __shfl_xor(acc.z, 32);
    acc.w += __shfl_xor(acc.w, 32);

    const float inv = 1.0f / fmaxf((float)d, 1.0f);
    const int which = lane >> 5, sub = lane & 31;
    float* orow = out + (size_t)node * OUT_W;

    if (half == 0) {
        if (which == 0) {
            f4 mean = {acc.x * inv, acc.y * inv, acc.z * inv, acc.w * inv};
            __builtin_nontemporal_store(mean, (f4*)(orow + F + sub * 4));   // cols 128..255
        } else {
            const f4 xv = *(const f4*)(x + (size_t)node * F + sub * 4);
            __builtin_nontemporal_store(xv, (f4*)(orow + sub * 4));         // cols 0..127
        }
    } else if (which == 0) {
        f4 mean = {acc.x * inv, acc.y * inv, acc.z * inv, acc.w * inv};
        __builtin_nontemporal_store(mean, (f4*)(orow + 2 * F + sub * 4));   // cols 256..383
    }
}

// ---------------------------------------------------------------------------
extern "C" void kernel_launch(void* const* d_in, const int* in_sizes, int n_in,
                              void* d_out, int out_size, void* d_ws, size_t ws_size,
                              hipStream_t stream) {
    const float* x          = (const float*)d_in[0];
    const int*   edge_index = (const int*)d_in[1];
    const float* edge_attr  = (const float*)d_in[2];

    const int N = in_sizes[0] / F;        // 10000 nodes
    const int E = in_sizes[1] / 2;        // 640000 edges
    const int* row = edge_index;          // destinations
    const int* col = edge_index + E;      // sources

    // workspace layout (ints)
    int* hist     = (int*)d_ws;                   // NBLK * N
    int* segstart = hist + (size_t)NBLK * N;      // N
    int* deg      = segstart + N;                 // N
    int* cursor   = deg + N;                      // 1
    int* eid      = cursor + 1;                   // E
    int* cid      = eid + E;                      // E

    float* out = (float*)d_out;

    const int chunk  = (E + NBLK - 1) / NBLK;
    const size_t smem = (size_t)N * sizeof(int);

    hist_kernel     <<<NBLK, HT, smem, stream>>>(row, hist, cursor, E, N, chunk);
    assign_kernel   <<<(N + 255) / 256, 256, 0, stream>>>(hist, segstart, deg, cursor, N);
    scatter_kernel  <<<NBLK, HT, smem, stream>>>(row, col, hist, eid, cid, E, N, chunk);
    aggregate_kernel<<<(2 * N + 3) / 4, 256, 0, stream>>>(x, edge_attr, segstart, deg,
                                                          eid, cid, out, N);
}

// Round 3
// 478.039 us; speedup vs baseline: 1.0554x; 1.0554x over previous
//
#include <hip/hip_runtime.h>

#define F      128
#define OUT_W  384
#define NBLK   64    // counting-sort blocks
#define HT     512   // threads per hist/scatter block

typedef __attribute__((ext_vector_type(4))) float f4;

// ---------------------------------------------------------------------------
// K1: per-block LDS-privatized histogram of destinations. No global atomics.
//     Also zeroes the segment cursor for K2.
// ---------------------------------------------------------------------------
__global__ __launch_bounds__(HT) void hist_kernel(const int* __restrict__ row,
                                                  int* __restrict__ hist,
                                                  int* __restrict__ cursor,
                                                  int E, int N, int chunk) {
    extern __shared__ int h[];
    const int t = threadIdx.x;
    if (blockIdx.x == 0 && t == 0) *cursor = 0;
    for (int i = t; i < N; i += HT) h[i] = 0;
    __syncthreads();
    const int lo = blockIdx.x * chunk;
    const int hi = min(lo + chunk, E);
    for (int i = lo + t; i < hi; i += HT) atomicAdd(&h[row[i]], 1);
    __syncthreads();
    int* dst = hist + (size_t)blockIdx.x * N;
    for (int i = t; i < N; i += HT) dst[i] = h[i];
}

// ---------------------------------------------------------------------------
// K2 (fused totals+scan+blockstart): per-node degree over the NBLK block-
// histograms, segment start via wave-aggregated global cursor (segment ORDER
// is arbitrary — only disjointness matters), then per-block running starts
// written back into hist. One kernel, no inter-block dependency.
// ---------------------------------------------------------------------------
__global__ void assign_kernel(int* __restrict__ hist, int* __restrict__ segstart,
                              int* __restrict__ deg, int* __restrict__ cursor, int N) {
    const int n = blockIdx.x * blockDim.x + threadIdx.x;
    const int lane = threadIdx.x & 63;
    int s = 0;
    if (n < N)
        for (int b = 0; b < NBLK; ++b) s += hist[(size_t)b * N + n];
    // wave-wide inclusive scan of s -> one atomic per wave
    int incl = s;
    for (int d = 1; d < 64; d <<= 1) {
        int v = __shfl_up(incl, d);
        if (lane >= d) incl += v;
    }
    int base = 0;
    if (lane == 63) base = atomicAdd(cursor, incl);
    base = __shfl(base, 63);
    const int start = base + incl - s;          // exclusive prefix within wave
    if (n >= N) return;
    segstart[n] = start;
    deg[n]      = s;
    int run = start;
    for (int b = 0; b < NBLK; ++b) {
        const size_t k = (size_t)b * N + n;
        const int v = hist[k];
        hist[k] = run;
        run += v;
    }
}

// ---------------------------------------------------------------------------
// K3: place edge ids. LDS cursors only; single scattered dword store per edge.
// (cid pre-gather reverted: it doubled scattered-write traffic for a gather
//  that was already latency-hidden in K4.)
// ---------------------------------------------------------------------------
__global__ __launch_bounds__(HT) void scatter_kernel(const int* __restrict__ row,
                                                     const int* __restrict__ hist,
                                                     int* __restrict__ eid,
                                                     int E, int N, int chunk) {
    extern __shared__ int cur[];
    const int t = threadIdx.x;
    const int* src = hist + (size_t)blockIdx.x * N;
    for (int i = t; i < N; i += HT) cur[i] = src[i];
    __syncthreads();
    const int lo = blockIdx.x * chunk;
    const int hi = min(lo + chunk, E);
    for (int i = lo + t; i < hi; i += HT) {
        const int p = atomicAdd(&cur[row[i]], 1);
        eid[p] = i;
    }
}

// ---------------------------------------------------------------------------
// K4: aggregation. 2 waves per node: half 0 sums x[col[eid[*]]] (L2/L3-
// resident), half 1 streams edge_attr[eid[*]] nontemporally. 8-edge unrolled
// inner loop -> 4 independent 16 B loads in flight per lane. No barriers.
// ---------------------------------------------------------------------------
template <bool NT>
__device__ __forceinline__ f4 row_ld(const float* __restrict__ mat, int id, int sub) {
    const f4* p = (const f4*)(mat + (size_t)id * F + sub * 4);
    return NT ? __builtin_nontemporal_load(p) : *p;
}

template <bool NT>
__device__ __forceinline__ void accum_half(const float* __restrict__ mat,
                                           const int* __restrict__ eid,
                                           const int* __restrict__ colmap,
                                           int start, int end, int lane, f4& acc) {
    const int which = lane >> 5;
    const int sub   = lane & 31;
    for (int base = start; base < end; base += 64) {
        const int m = min(64, end - base);
        int idx = base + lane;
        if (idx >= end) idx = end - 1;          // clamp; lanes >= m never selected
        int myid = eid[idx];
        if (colmap) myid = colmap[myid];        // wave-uniform branch
        int i = 0;
        for (; i + 8 <= m; i += 8) {
            const int id0 = __shfl(myid, i + 0 + which);
            const int id1 = __shfl(myid, i + 2 + which);
            const int id2 = __shfl(myid, i + 4 + which);
            const int id3 = __shfl(myid, i + 6 + which);
            const f4 v0 = row_ld<NT>(mat, id0, sub);
            const f4 v1 = row_ld<NT>(mat, id1, sub);
            const f4 v2 = row_ld<NT>(mat, id2, sub);
            const f4 v3 = row_ld<NT>(mat, id3, sub);
            acc += v0; acc += v1; acc += v2; acc += v3;
        }
        const int full = m & ~1;
        for (; i < full; i += 2) {
            const int id = __shfl(myid, i + which);
            acc += row_ld<NT>(mat, id, sub);
        }
        if (m & 1) {
            const int id = __shfl(myid, full);
            if (which == 0) acc += row_ld<NT>(mat, id, sub);
        }
    }
}

__global__ __launch_bounds__(256) void aggregate_kernel(
    const float* __restrict__ x, const float* __restrict__ edge_attr,
    const int* __restrict__ col, const int* __restrict__ segstart,
    const int* __restrict__ deg, const int* __restrict__ eid,
    float* __restrict__ out, int N) {

    const int wave = threadIdx.x >> 6;
    const int lane = threadIdx.x & 63;
    const int wid  = blockIdx.x * 4 + wave;
    const int node = wid >> 1;
    const int half = wid & 1;
    if (node >= N) return;

    const int start = segstart[node];
    const int d     = deg[node];
    const int end   = start + d;

    f4 acc = {0.f, 0.f, 0.f, 0.f};
    if (half == 0) accum_half<false>(x,         eid, col,     start, end, lane, acc);
    else           accum_half<true >(edge_attr, eid, nullptr, start, end, lane, acc);

    // fold odd-edge lanes (32..63) into even-edge lanes (0..31)
    acc.x += __shfl_xor(acc.x, 32);
    acc.y += __shfl_xor(acc.y, 32);
    acc.z += __shfl_xor(acc.z, 32);
    acc.w += __shfl_xor(acc.w, 32);

    const float inv = 1.0f / fmaxf((float)d, 1.0f);
    const int which = lane >> 5, sub = lane & 31;
    float* orow = out + (size_t)node * OUT_W;

    if (half == 0) {
        if (which == 0) {
            f4 mean = {acc.x * inv, acc.y * inv, acc.z * inv, acc.w * inv};
            __builtin_nontemporal_store(mean, (f4*)(orow + F + sub * 4));   // cols 128..255
        } else {
            const f4 xv = *(const f4*)(x + (size_t)node * F + sub * 4);
            __builtin_nontemporal_store(xv, (f4*)(orow + sub * 4));         // cols 0..127
        }
    } else if (which == 0) {
        f4 mean = {acc.x * inv, acc.y * inv, acc.z * inv, acc.w * inv};
        __builtin_nontemporal_store(mean, (f4*)(orow + 2 * F + sub * 4));   // cols 256..383
    }
}

// ---------------------------------------------------------------------------
extern "C" void kernel_launch(void* const* d_in, const int* in_sizes, int n_in,
                              void* d_out, int out_size, void* d_ws, size_t ws_size,
                              hipStream_t stream) {
    const float* x          = (const float*)d_in[0];
    const int*   edge_index = (const int*)d_in[1];
    const float* edge_attr  = (const float*)d_in[2];

    const int N = in_sizes[0] / F;        // 10000 nodes
    const int E = in_sizes[1] / 2;        // 640000 edges
    const int* row = edge_index;          // destinations
    const int* col = edge_index + E;      // sources

    // workspace layout (ints)
    int* hist     = (int*)d_ws;                   // NBLK * N
    int* segstart = hist + (size_t)NBLK * N;      // N
    int* deg      = segstart + N;                 // N
    int* cursor   = deg + N;                      // 1
    int* eid      = cursor + 1;                   // E

    float* out = (float*)d_out;

    const int chunk  = (E + NBLK - 1) / NBLK;
    const size_t smem = (size_t)N * sizeof(int);

    hist_kernel     <<<NBLK, HT, smem, stream>>>(row, hist, cursor, E, N, chunk);
    assign_kernel   <<<(N + 255) / 256, 256, 0, stream>>>(hist, segstart, deg, cursor, N);
    scatter_kernel  <<<NBLK, HT, smem, stream>>>(row, hist, eid, E, N, chunk);
    aggregate_kernel<<<(2 * N + 3) / 4, 256, 0, stream>>>(x, edge_attr, col, segstart,
                                                          deg, eid, out, N);
}